// Round 4
// baseline (105.521 us; speedup 1.0000x reference)
//
#include <hip/hip_runtime.h>

typedef short bf16x8 __attribute__((ext_vector_type(8)));
typedef unsigned short u16;
typedef u16 u16x8 __attribute__((ext_vector_type(8)));
typedef float f32x4 __attribute__((ext_vector_type(4)));

constexpr int TPB  = 256;
constexpr int RPB  = 64;    // rows per block
constexpr int DIM  = 300;   // embedding dim (9*32 + 12)
constexpr int H1N  = 64;
constexpr int NA   = 18;
constexpr int NK   = 32;
constexpr int NC   = 384;
constexpr float LOG_HALF = -0.6931471805599453f;

__device__ __forceinline__ float fast_sigmoid(float z) {
    return __builtin_amdgcn_rcpf(1.0f + __expf(-z));
}
// stable log(sigmoid(z))
__device__ __forceinline__ float lsig(float z) {
    return fminf(z, 0.0f) - __logf(1.0f + __expf(-fabsf(z)));
}
// f32 -> bf16 (RNE)
__device__ __forceinline__ u16 f2bf(float f) {
    unsigned u = __builtin_bit_cast(unsigned, f);
    unsigned r = (u + 0x7FFFu + ((u >> 16) & 1u)) >> 16;
    return (u16)r;
}
__device__ __forceinline__ float bf2f(u16 h) {
    return __builtin_bit_cast(float, ((unsigned)h) << 16);
}
// spread 8 bits to 8 nibbles (bit a -> bit 4a)
__device__ __forceinline__ unsigned spread8(unsigned v) {
    v = (v | (v << 12)) & 0x000F000Fu;
    v = (v | (v << 6))  & 0x03030303u;
    v = (v | (v << 3))  & 0x11111111u;
    return v;
}

__global__ __launch_bounds__(TPB, 4)
void fused_mf2(const float* __restrict__ x, const float* __restrict__ y,
               const float* __restrict__ ob, const float* __restrict__ cbf,
               const float* __restrict__ W1, const float* __restrict__ b1,
               const float* __restrict__ W2, const float* __restrict__ b2,
               const float* __restrict__ W3, const float* __restrict__ b3,
               const int* __restrict__ neg_idx,
               float* __restrict__ out_wu, float2* __restrict__ blk_part)
{
    __shared__ u16 h1s[RPB * H1N];     // 8 KiB, XOR-swizzled bf16 h1
    __shared__ unsigned cb_bits[NC];   // packed binary codebook rows
    __shared__ float wsum[4];
    __shared__ int   wcnt[4];

    const int tid  = threadIdx.x;
    const int lane = tid & 63;
    const int wv   = tid >> 6;
    const int rh   = wv >> 1;          // row half (32 rows)
    const int chh  = wv & 1;           // col half (32 cols)
    const int kg   = (lane >> 4) * 8;  // k-group within K=32 step
    const int l15  = lane & 15;
    const long brow = (long)blockIdx.x * RPB;
    const float* xg = x + brow * DIM;

    // ---- codebook bitmasks (rows are exactly 0/1) ----
    for (int c = tid; c < NC; c += TPB) {
        unsigned bits = 0u;
        #pragma unroll
        for (int a = 0; a < NA; ++a)
            bits |= (cbf[c * NA + a] != 0.0f) ? (1u << a) : 0u;
        cb_bits[c] = bits;
    }

    // ---- x @ W1 via MFMA, A-frags straight from global (no LDS staging) ----
    f32x4 acc[2][2];
    #pragma unroll
    for (int rt = 0; rt < 2; ++rt)
        #pragma unroll
        for (int ct = 0; ct < 2; ++ct)
            acc[rt][ct] = (f32x4){0.f, 0.f, 0.f, 0.f};

    #pragma unroll
    for (int half = 0; half < 2; ++half) {
        // B-frags for this K-half (40 VGPR peak)
        bf16x8 bfr[2][5];
        #pragma unroll
        for (int ct = 0; ct < 2; ++ct) {
            const int col = chh * 32 + ct * 16 + l15;
            #pragma unroll
            for (int k5 = 0; k5 < 5; ++k5) {
                const int kt = half * 5 + k5;
                #pragma unroll
                for (int r = 0; r < 8; ++r) {
                    const int kk = kt * 32 + kg + r;
                    const float w = (kk < DIM) ? W1[kk * H1N + col] : 0.0f;
                    bfr[ct][k5][r] = (short)f2bf(w);
                }
            }
        }
        #pragma unroll
        for (int k5 = 0; k5 < 5; ++k5) {
            const int kt = half * 5 + k5;
            const int k0 = kt * 32 + kg;
            bf16x8 afr[2];
            #pragma unroll
            for (int rt = 0; rt < 2; ++rt) {
                const float* xp = xg + (rh * 32 + rt * 16 + l15) * DIM + k0;
                float4 v0, v1;
                if (kt < 9) {                       // fully in-bounds (k<288+24+8<=287..)
                    v0 = *(const float4*)xp;
                    v1 = *(const float4*)(xp + 4);
                } else {                            // kt==9: k in [288,320), valid < 300
                    const float4 z = make_float4(0.f, 0.f, 0.f, 0.f);
                    v0 = (k0     < DIM) ? *(const float4*)xp       : z;
                    v1 = (k0 + 4 < DIM) ? *(const float4*)(xp + 4) : z;
                }
                afr[rt][0] = (short)f2bf(v0.x); afr[rt][1] = (short)f2bf(v0.y);
                afr[rt][2] = (short)f2bf(v0.z); afr[rt][3] = (short)f2bf(v0.w);
                afr[rt][4] = (short)f2bf(v1.x); afr[rt][5] = (short)f2bf(v1.y);
                afr[rt][6] = (short)f2bf(v1.z); afr[rt][7] = (short)f2bf(v1.w);
            }
            #pragma unroll
            for (int rt = 0; rt < 2; ++rt)
                #pragma unroll
                for (int ct = 0; ct < 2; ++ct)
                    acc[rt][ct] = __builtin_amdgcn_mfma_f32_16x16x32_bf16(
                        afr[rt], bfr[ct][k5], acc[rt][ct], 0, 0, 0);
        }
    }

    // ---- epilogue: bias + sigmoid -> h1s (bf16, XOR-swizzled) ----
    const float b1v0 = b1[chh * 32 + l15];
    const float b1v1 = b1[chh * 32 + 16 + l15];
    #pragma unroll
    for (int rt = 0; rt < 2; ++rt) {
        #pragma unroll
        for (int ct = 0; ct < 2; ++ct) {
            const int col = chh * 32 + ct * 16 + l15;
            const float bv = ct ? b1v1 : b1v0;
            #pragma unroll
            for (int j = 0; j < 4; ++j) {
                const int row = rh * 32 + rt * 16 + (lane >> 4) * 4 + j;  // m89 C/D map
                const float h = fast_sigmoid(acc[rt][ct][j] + bv);
                h1s[(row * H1N + col) ^ ((row & 7) << 3)] = f2bf(h);
            }
        }
    }
    __syncthreads();

    // ================= downstream: 4 lanes per row =================
    const int rloc = wv * 16 + (lane >> 2);   // row within block
    const int p    = lane & 3;                // part (j-split)
    const long b   = brow + rloc;

    // h1 row into registers (4-lane broadcast per address -> conflict-light)
    u16x8 h1r[8];
    #pragma unroll
    for (int q = 0; q < 8; ++q)
        h1r[q] = *(const u16x8*)(h1s + ((rloc * H1N + q * 8) ^ ((rloc & 7) << 3)));

    // ---- h1 @ W2 : part p owns cols p*8..p*8+7 ----
    const float4 b2a = *(const float4*)(b2 + p * 8);
    const float4 b2b = *(const float4*)(b2 + p * 8 + 4);
    float acc2[8] = {b2a.x, b2a.y, b2a.z, b2a.w, b2b.x, b2b.y, b2b.z, b2b.w};
    #pragma unroll
    for (int i = 0; i < H1N; ++i) {
        const float hv = bf2f((u16)h1r[i >> 3][i & 7]);
        const float4 wa = *(const float4*)(W2 + i * 32 + p * 8);
        const float4 wb = *(const float4*)(W2 + i * 32 + p * 8 + 4);
        acc2[0] = fmaf(hv, wa.x, acc2[0]);
        acc2[1] = fmaf(hv, wa.y, acc2[1]);
        acc2[2] = fmaf(hv, wa.z, acc2[2]);
        acc2[3] = fmaf(hv, wa.w, acc2[3]);
        acc2[4] = fmaf(hv, wb.x, acc2[4]);
        acc2[5] = fmaf(hv, wb.y, acc2[5]);
        acc2[6] = fmaf(hv, wb.z, acc2[6]);
        acc2[7] = fmaf(hv, wb.w, acc2[7]);
    }
    float h2[8];
    #pragma unroll
    for (int j = 0; j < 8; ++j) h2[j] = fast_sigmoid(acc2[j]);

    // ---- h2 @ W3 : i-split, reduce over parts ----
    float wu[NA];
    #pragma unroll
    for (int a = 0; a < NA; ++a) wu[a] = 0.0f;
    #pragma unroll
    for (int uI = 0; uI < 8; ++uI) {
        const float hv = h2[uI];
        const float* w3r = W3 + (p * 8 + uI) * NA;
        #pragma unroll
        for (int a = 0; a < NA; ++a) wu[a] = fmaf(hv, w3r[a], wu[a]);
    }
    #pragma unroll
    for (int a = 0; a < NA; ++a) {
        wu[a] += __shfl_xor(wu[a], 1);
        wu[a] += __shfl_xor(wu[a], 2);
        wu[a] += b3[a];
    }

    // ---- select owned wu (attrs p*4..p*4+3 and 16+p for p<2) ----
    float wA0, wA1, wA2, wA3, wT;
    if (p == 0)      { wA0=wu[0];  wA1=wu[1];  wA2=wu[2];  wA3=wu[3];  wT=wu[16]; }
    else if (p == 1) { wA0=wu[4];  wA1=wu[5];  wA2=wu[6];  wA3=wu[7];  wT=wu[17]; }
    else if (p == 2) { wA0=wu[8];  wA1=wu[9];  wA2=wu[10]; wA3=wu[11]; wT=0.f; }
    else             { wA0=wu[12]; wA1=wu[13]; wA2=wu[14]; wA3=wu[15]; wT=0.f; }

    // store W_user (float2-vectorized, 8B aligned by construction)
    float* ow = out_wu + b * NA + p * 4;
    *(float2*)ow       = make_float2(wA0, wA1);
    *(float2*)(ow + 2) = make_float2(wA2, wA3);
    if (p < 2) out_wu[b * NA + 16 + p] = wT;

    // loads of ob / y (float2)
    const float* obr = ob + b * NA + p * 4;
    const float2 oA = *(const float2*)obr, oB = *(const float2*)(obr + 2);
    const float  oT = (p < 2) ? ob[b * NA + 16 + p] : 0.f;
    const float* yr = y + b * NA + p * 4;
    const float2 yA = *(const float2*)yr, yB = *(const float2*)(yr + 2);
    const float  yT = (p < 2) ? y[b * NA + 16 + p] : 0.f;

    const float wcv[4] = {wA0 * oA.x, wA1 * oA.y, wA2 * oB.x, wA3 * oB.y};
    const float yvv[4] = {yA.x, yA.y, yB.x, yB.y};
    const float wcT = wT * oT;
    float ssum = wcv[0] + wcv[1] + wcv[2] + wcv[3] + wcT;
    ssum += __shfl_xor(ssum, 1);
    ssum += __shfl_xor(ssum, 2);
    const int mask = (ssum != 0.0f) ? 1 : 0;

    // ---- negatives: per-part (8 negs) nibble-packed per-attr counts ----
    const int4* nb = reinterpret_cast<const int4*>(neg_idx + b * NK + p * 8);
    const int4 n0 = nb[0], n1 = nb[1];
    const int ids[8] = {n0.x, n0.y, n0.z, n0.w, n1.x, n1.y, n1.z, n1.w};
    unsigned c0 = 0u, c1 = 0u, c2 = 0u;
    #pragma unroll
    for (int kk = 0; kk < 8; ++kk) {
        const unsigned bits = cb_bits[ids[kk]];
        c0 += spread8(bits & 0xFFu);
        c1 += spread8((bits >> 8) & 0xFFu);
        const unsigned t = (bits >> 16) & 3u;
        c2 += (t | (t << 3)) & 0x11u;
    }
    unsigned e0 = c0 & 0x0F0F0F0Fu;          // attrs 0,2,4,6
    unsigned e1 = (c0 >> 4) & 0x0F0F0F0Fu;   // attrs 1,3,5,7
    unsigned e2 = c1 & 0x0F0F0F0Fu;          // attrs 8,10,12,14
    unsigned e3 = (c1 >> 4) & 0x0F0F0F0Fu;   // attrs 9,11,13,15
    unsigned e4 = (c2 & 15u) | (((c2 >> 4) & 15u) << 8);  // attrs 16,17
    e0 += __shfl_xor((int)e0, 1); e0 += __shfl_xor((int)e0, 2);
    e1 += __shfl_xor((int)e1, 1); e1 += __shfl_xor((int)e1, 2);
    e2 += __shfl_xor((int)e2, 1); e2 += __shfl_xor((int)e2, 2);
    e3 += __shfl_xor((int)e3, 1); e3 += __shfl_xor((int)e3, 2);
    e4 += __shfl_xor((int)e4, 1); e4 += __shfl_xor((int)e4, 2);

    // ---- pos_log + neg_log on owned attrs ----
    float rsum = 0.0f;
    #pragma unroll
    for (int i = 0; i < 4; ++i) {
        const unsigned regE = ((i & 1) == 0) ? ((p < 2) ? e0 : e2)
                                             : ((p < 2) ? e1 : e3);
        const int sh = (((p & 1) * 2) + (i >> 1)) * 8;
        const int cn = (int)((regE >> sh) & 0xFFu);
        const float w = wcv[i];
        const float pos = (yvv[i] != 0.0f) ? lsig(w) : LOG_HALF;
        rsum += pos + (float)cn * lsig(-w) + (float)(NK - cn) * LOG_HALF;
    }
    if (p < 2) {
        const int cn = (int)((e4 >> (p * 8)) & 0xFFu);
        const float pos = (yT != 0.0f) ? lsig(wcT) : LOG_HALF;
        rsum += pos + (float)cn * lsig(-wcT) + (float)(NK - cn) * LOG_HALF;
    }
    rsum += __shfl_xor(rsum, 1);
    rsum += __shfl_xor(rsum, 2);

    // ---- block reduction (no atomics): per-block partial to workspace ----
    float v = (p == 0 && mask) ? rsum : 0.0f;
    int   m = (p == 0) ? mask : 0;
    #pragma unroll
    for (int off = 32; off > 0; off >>= 1) {
        v += __shfl_down(v, off);
        m += __shfl_down(m, off);
    }
    if (lane == 0) { wsum[wv] = v; wcnt[wv] = m; }
    __syncthreads();
    if (tid == 0) {
        const float s = wsum[0] + wsum[1] + wsum[2] + wsum[3];
        const int   c = wcnt[0] + wcnt[1] + wcnt[2] + wcnt[3];
        blk_part[blockIdx.x] = make_float2(s, (float)c);
    }
}

__global__ void finalize_k(const float2* __restrict__ part, int nblk,
                           float* __restrict__ out_loss) {
    __shared__ float ss[4], sc[4];
    float s = 0.f, c = 0.f;
    for (int i = threadIdx.x; i < nblk; i += 256) {
        const float2 v = part[i];
        s += v.x; c += v.y;
    }
    #pragma unroll
    for (int off = 32; off > 0; off >>= 1) {
        s += __shfl_down(s, off);
        c += __shfl_down(c, off);
    }
    const int wv = threadIdx.x >> 6;
    if ((threadIdx.x & 63) == 0) { ss[wv] = s; sc[wv] = c; }
    __syncthreads();
    if (threadIdx.x == 0) {
        const float S = ss[0] + ss[1] + ss[2] + ss[3];
        const float C = sc[0] + sc[1] + sc[2] + sc[3];
        out_loss[0] = -S / fmaxf(C, 1.0f);
    }
}

extern "C" void kernel_launch(void* const* d_in, const int* in_sizes, int n_in,
                              void* d_out, int out_size, void* d_ws, size_t ws_size,
                              hipStream_t stream)
{
    const float* x   = (const float*)d_in[0];
    const float* y   = (const float*)d_in[1];
    const float* ob  = (const float*)d_in[2];
    const float* cb  = (const float*)d_in[3];
    const float* W1  = (const float*)d_in[4];
    const float* b1  = (const float*)d_in[5];
    const float* W2  = (const float*)d_in[6];
    const float* b2  = (const float*)d_in[7];
    const float* W3  = (const float*)d_in[8];
    const float* b3  = (const float*)d_in[9];
    const int*   neg = (const int*)d_in[10];

    const int B = in_sizes[0] / DIM;        // 131072
    const int nblk = B / RPB;               // 2048

    float*  out_wu = (float*)d_out;
    float2* part   = (float2*)d_ws;         // 16 KiB scratch

    fused_mf2<<<nblk, TPB, 0, stream>>>(x, y, ob, cb, W1, b1, W2, b2, W3, b3,
                                        neg, out_wu, part);
    finalize_k<<<1, TPB, 0, stream>>>(part, nblk, out_wu + (long)B * NA);
}